// Round 4
// baseline (33.899 us; speedup 1.0000x reference)
//
#include <hip/hip_runtime.h>

// Lucas-Kanade optical flow, fused single kernel, packed-fp32 (v_pk_*_f32).
// Input:  image_prev, image_next  (1,1,2048,2048) fp32
// Output: (1,2,2048,2048) fp32  -> u at [0:H*W], v at [H*W:2*H*W]
//
// Numerics: the reference's det/numerators cancel catastrophically; we must
// reproduce its fp32 op-for-op rounding. `#pragma clang fp contract(off)`
// disables mul+add fusion (hipcc default is -ffp-contract=fast); no fast-math
// flags are passed so no reassociation happens. Packing uses float2 lanes for
// INDEPENDENT accumulation chains only -> bit-identical per component.

#pragma clang fp contract(off)

typedef float v2f __attribute__((ext_vector_type(2)));

#define IMG_H 2048
#define IMG_W 2048
#define TW 32          // output cols per block
#define TH 32          // output rows per block
#define LDSW 36        // cols 0..31 interior, 32 = right halo, 34 = left halo

__global__ __launch_bounds__(256, 4)
void lk_flow_v4(const float* __restrict__ prev,
                const float* __restrict__ next,
                float* __restrict__ out) {
    #pragma clang fp contract(off)
    __shared__ __align__(16) float srx[TH + 2][LDSW];
    __shared__ __align__(16) float sry[TH + 2][LDSW];
    __shared__ __align__(16) float srt[TH + 2][LDSW];

    const int r0 = (int)blockIdx.y * TH;
    const int c0 = (int)blockIdx.x * TW;
    const int tid = (int)threadIdx.y * 8 + (int)threadIdx.x;

    // ---- Phase A (interior): res rows r0-1+hr, 8 chunks of 4 aligned cols ----
    for (int t = tid; t < (TH + 2) * 8; t += 256) {
        const int hr = t >> 3;
        const int ch = t & 7;
        const int a  = r0 - 1 + hr;
        const int b  = c0 + ch * 4;
        float rx[4], ry[4], rt[4];
        if (a >= 0 && a < IMG_H) {
            const int a1 = (a + 1 == IMG_H) ? (IMG_H - 2) : (a + 1);  // reflect (after)
            const int b4 = (b + 4 == IMG_W) ? (IMG_W - 2) : (b + 4);  // reflect (after)
            const float4 P0 = *reinterpret_cast<const float4*>(&prev[(size_t)a  * IMG_W + b]);
            const float4 P1 = *reinterpret_cast<const float4*>(&prev[(size_t)a1 * IMG_W + b]);
            const float4 Q0 = *reinterpret_cast<const float4*>(&next[(size_t)a  * IMG_W + b]);
            const float4 Q1 = *reinterpret_cast<const float4*>(&next[(size_t)a1 * IMG_W + b]);
            // m[k] = (prev,next) at row a, col b+k;  n[k] = same at row a1
            const v2f m[5] = { {P0.x, Q0.x}, {P0.y, Q0.y}, {P0.z, Q0.z}, {P0.w, Q0.w},
                               {prev[(size_t)a  * IMG_W + b4], next[(size_t)a  * IMG_W + b4]} };
            const v2f n[5] = { {P1.x, Q1.x}, {P1.y, Q1.y}, {P1.z, Q1.z}, {P1.w, Q1.w},
                               {prev[(size_t)a1 * IMG_W + b4], next[(size_t)a1 * IMG_W + b4]} };
            #pragma unroll
            for (int k = 0; k < 4; ++k) {
                // bit-equal to the reference's left-to-right order:
                //   gx = ((-p00+p01)-p10)+p11 = ((p01-p00)-p10)+p11
                //   gy = ((-p00-p01)+p10)+p11 = ((p10-(p00+p01))+p11   (-x-y == -(x+y) exactly)
                //   gs = (( p00+p01)+p10)+p11
                const v2f A  = m[k] + m[k + 1];
                const v2f D  = m[k + 1] - m[k];
                const v2f GX = (D - n[k]) + n[k + 1];
                const v2f GY = (n[k] - A) + n[k + 1];
                const v2f GS = (A + n[k]) + n[k + 1];
                rx[k] = 0.5f * (GX.x + GX.y);       // 0.5*(gxp+gxq)
                ry[k] = 0.5f * (GY.x + GY.y);
                rt[k] = 0.5f * (GS.y - GS.x);       // 0.5*(-gsp+gsq)
            }
        } else {
            #pragma unroll
            for (int k = 0; k < 4; ++k) { rx[k] = 0.f; ry[k] = 0.f; rt[k] = 0.f; }
        }
        const int lc = ch * 4;
        *reinterpret_cast<float4*>(&srx[hr][lc]) = make_float4(rx[0], rx[1], rx[2], rx[3]);
        *reinterpret_cast<float4*>(&sry[hr][lc]) = make_float4(ry[0], ry[1], ry[2], ry[3]);
        *reinterpret_cast<float4*>(&srt[hr][lc]) = make_float4(rt[0], rt[1], rt[2], rt[3]);
    }

    // ---- Phase A (edges): image col c0-1 -> LDS col 34, image col c0+32 -> LDS col 32
    for (int t = tid; t < (TH + 2) * 2; t += 256) {
        const int hr = t >> 1;
        const int e  = t & 1;
        const int a  = r0 - 1 + hr;
        const int bc = e ? (c0 + TW) : (c0 - 1);
        const int lc = e ? TW : 34;
        float rx = 0.f, ry = 0.f, rt = 0.f;
        if (a >= 0 && a < IMG_H && bc >= 0 && bc < IMG_W) {
            const int a1 = (a + 1 == IMG_H) ? (IMG_H - 2) : (a + 1);
            const int b1 = (bc + 1 == IMG_W) ? (IMG_W - 2) : (bc + 1);
            const v2f m0 = { prev[(size_t)a  * IMG_W + bc], next[(size_t)a  * IMG_W + bc] };
            const v2f m1 = { prev[(size_t)a  * IMG_W + b1], next[(size_t)a  * IMG_W + b1] };
            const v2f n0 = { prev[(size_t)a1 * IMG_W + bc], next[(size_t)a1 * IMG_W + bc] };
            const v2f n1 = { prev[(size_t)a1 * IMG_W + b1], next[(size_t)a1 * IMG_W + b1] };
            const v2f A  = m0 + m1;
            const v2f D  = m1 - m0;
            const v2f GX = (D - n0) + n1;
            const v2f GY = (n0 - A) + n1;
            const v2f GS = (A + n0) + n1;
            rx = 0.5f * (GX.x + GX.y);
            ry = 0.5f * (GY.x + GY.y);
            rt = 0.5f * (GS.y - GS.x);
        }
        srx[hr][lc] = rx; sry[hr][lc] = ry; srt[hr][lc] = rt;
    }

    __syncthreads();

    // ---- Phase B: each thread -> 1 output row x 4 output cols ----
    const int tx = (int)threadIdx.x;    // 0..7
    const int ty = (int)threadIdx.y;    // 0..31 = local output row
    const int jb = tx * 4;
    const int cm1 = (tx == 0) ? 34 : (jb - 1);   // LDS col of res col (c0+jb-1)

    // packed accumulators: accA=(Sxx,Syy), accB=(Sxy,Sxt), accC=Syt
    v2f accA[4], accB[4];
    float accC[4];
    #pragma unroll
    for (int q = 0; q < 4; ++q) { accA[q] = (v2f){0.f, 0.f}; accB[q] = (v2f){0.f, 0.f}; accC[q] = 0.f; }

    #pragma unroll 1
    for (int rr = 0; rr < 3; ++rr) {
        const int hr = ty + rr;   // res rows (i-1), i, (i+1)
        const float4 vx = *reinterpret_cast<const float4*>(&srx[hr][jb]);
        const float X[6] = { srx[hr][cm1], vx.x, vx.y, vx.z, vx.w, srx[hr][jb + 4] };
        const float4 vy = *reinterpret_cast<const float4*>(&sry[hr][jb]);
        const float Y[6] = { sry[hr][cm1], vy.x, vy.y, vy.z, vy.w, sry[hr][jb + 4] };
        const float4 vt = *reinterpret_cast<const float4*>(&srt[hr][jb]);
        const float T[6] = { srt[hr][cm1], vt.x, vt.y, vt.z, vt.w, srt[hr][jb + 4] };
        v2f PA[6], PB[6];
        float PC[6];
        #pragma unroll
        for (int k = 0; k < 6; ++k) {
            const v2f xy = { X[k], Y[k] };
            PA[k] = xy * xy;                      // (rx*rx, ry*ry)
            const v2f xt = { X[k], T[k] };
            const v2f yx = { Y[k], X[k] };
            PB[k] = xt * yx;                      // (rx*ry, rt*rx)
            PC[k] = T[k] * Y[k];                  // rt*ry
        }
        // exact reference box3 order per output & array: dr outer (rr asc), dc inner
        #pragma unroll
        for (int q = 0; q < 4; ++q) {
            accA[q] += PA[q]; accA[q] += PA[q + 1]; accA[q] += PA[q + 2];
            accB[q] += PB[q]; accB[q] += PB[q + 1]; accB[q] += PB[q + 2];
            accC[q] += PC[q]; accC[q] += PC[q + 1]; accC[q] += PC[q + 2];
        }
    }

    const int i = r0 + ty;
    float uo[4], vo[4];
    #pragma unroll
    for (int q = 0; q < 4; ++q) {
        const float Sxx = accA[q].x, Syy = accA[q].y;
        const float Sxy = accB[q].x, Sxt = accB[q].y;
        const float Syt = accC[q];
        const float t1 = Sxx * Syy;
        const float t2 = Sxy * Sxy;
        const float det = t1 - t2;
        float u = 0.f, v = 0.f;
        if (det != 0.f) {
            const float inv = __builtin_amdgcn_rcpf(det);  // 1-ulp rcp, ample margin
            const float n1 = Syy * Sxt - Sxy * Syt;
            const float n2 = Sxx * Syt - Sxy * Sxt;
            u = n1 * inv;
            v = n2 * inv;
        }
        const int j = c0 + jb + q;
        if (i == 0 || j == 0) { u = 0.f; v = 0.f; }  // reference zeroes row0/col0
        uo[q] = u; vo[q] = v;
    }
    float4 U = {uo[0], uo[1], uo[2], uo[3]};
    float4 V = {vo[0], vo[1], vo[2], vo[3]};
    *reinterpret_cast<float4*>(&out[(size_t)i * IMG_W + (c0 + jb)]) = U;
    *reinterpret_cast<float4*>(&out[(size_t)(IMG_H + i) * IMG_W + (c0 + jb)]) = V;
}

extern "C" void kernel_launch(void* const* d_in, const int* in_sizes, int n_in,
                              void* d_out, int out_size, void* d_ws, size_t ws_size,
                              hipStream_t stream) {
    const float* prev = (const float*)d_in[0];
    const float* next = (const float*)d_in[1];
    float* out = (float*)d_out;
    dim3 grid(IMG_W / TW, IMG_H / TH);   // 64 x 64
    dim3 block(8, 32);
    lk_flow_v4<<<grid, block, 0, stream>>>(prev, next, out);
}